// Round 25
// baseline (135.155 us; speedup 1.0000x reference)
//
#include <hip/hip_runtime.h>
#include <hip/hip_bf16.h>
#include <hip/hip_fp16.h>

typedef __attribute__((ext_vector_type(8))) _Float16 half8v;  // 8 fp16 = 4 VGPR
typedef __attribute__((ext_vector_type(4))) float f32x4;

// ---------- packed weights (written by prep_kernel every launch) ----------
__device__ __align__(16) float g_w0T[256 * 512];                  // fp32 [c][j] (fallback/debug)
__device__ __align__(16) unsigned short g_wa0[32 * 8 * 64 * 8];   // a0 A-frags fp16 [jt][k0][l][e]
__device__ __align__(16) unsigned short g_wp1[8 * 8 * 64 * 8];    // L1 A-frags fp16 (64KB)
__device__ __align__(16) unsigned short g_wp2[4 * 4 * 64 * 8];    // L2 (16KB)
__device__ __align__(16) unsigned short g_wp3[2 * 2 * 64 * 8];    // L3 (4KB)

// ---------- helpers ----------
__device__ __forceinline__ float lrelu(float x) { return x >= 0.f ? x : 0.01f * x; }
__device__ __forceinline__ unsigned short f2hu(float x) {
    _Float16 h = (_Float16)x; return *(unsigned short*)&h;
}
__device__ __forceinline__ unsigned short f2us(float x) {   // bf16 (mode-1 candT only)
    __hip_bfloat16 h = __float2bfloat16(x); return *(unsigned short*)&h;
}
__device__ __forceinline__ float us2f(unsigned short u) {
    union { unsigned i; float f; } c; c.i = ((unsigned)u) << 16; return c.f;
}
__device__ __forceinline__ uint2 pack_h4(const f32x4& a) {
    unsigned short h[4];
#pragma unroll
    for (int i = 0; i < 4; ++i) h[i] = f2hu(lrelu(a[i]));
    uint2 r;
    r.x = (unsigned)h[0] | ((unsigned)h[1] << 16);
    r.y = (unsigned)h[2] | ((unsigned)h[3] << 16);
    return r;
}

// ---------- prep: w0T fp32, a0/L1..L3 A-frags (fp16) ----------
__global__ __launch_bounds__(256) void prep_kernel(
    const float* __restrict__ w0, const float* __restrict__ w1,
    const float* __restrict__ w2, const float* __restrict__ w3)
{
    int id = blockIdx.x * 256 + threadIdx.x;
    int stride = gridDim.x * 256;
    for (int i = id; i < 256 * 512; i += stride) {        // w0T[c][j] fp32
        int c = i >> 9, j = i & 511;
        g_w0T[i] = (j < 256) ? w0[j * 512 + c] : w0[(j - 256) * 512 + 256 + c];
    }
    for (int i = id; i < 32 * 8 * 64 * 8; i += stride) {  // a0 A-frags
        int e = i & 7, l = (i >> 3) & 63, k0 = (i >> 9) & 7, jt = i >> 12;
        int c = k0 * 32 + ((l >> 4) * 8) + e;
        int j = jt * 16 + (l & 15);
        float v = (j < 256) ? w0[j * 512 + c] : w0[(j - 256) * 512 + 256 + c];
        g_wa0[i] = f2hu(v);
    }
    for (int i = id; i < 8 * 8 * 64 * 8; i += stride) {   // L1: 128x256
        int e = i & 7, l = (i >> 3) & 63, k0 = (i >> 9) & 7, m = i >> 12;
        int oc = m * 16 + (l & 15), c = k0 * 32 + ((l >> 4) * 8) + e;
        g_wp1[i] = f2hu(w1[oc * 256 + c]);
    }
    for (int i = id; i < 4 * 4 * 64 * 8; i += stride) {   // L2: 64x128
        int e = i & 7, l = (i >> 3) & 63, k0 = (i >> 9) & 3, m = i >> 11;
        int oc = m * 16 + (l & 15), c = k0 * 32 + ((l >> 4) * 8) + e;
        g_wp2[i] = f2hu(w2[oc * 128 + c]);
    }
    for (int i = id; i < 2 * 2 * 64 * 8; i += stride) {   // L3: 32x64
        int e = i & 7, l = (i >> 3) & 63, k0 = (i >> 9) & 1, m = i >> 10;
        int oc = m * 16 + (l & 15), c = k0 * 32 + ((l >> 4) * 8) + e;
        g_wp3[i] = f2hu(w3[oc * 64 + c]);
    }
}

// ---------- front_kernel: a0 (blocks 0..1663, incl. template A0t) | transpose (1664..2303) ----------
__global__ __launch_bounds__(256) void front_kernel(
    const float* __restrict__ cand, const float* __restrict__ tf,
    float* __restrict__ A0f, float* __restrict__ A0t,
    float* __restrict__ ctF, unsigned short* __restrict__ ctH, int mode)
{
    __shared__ __align__(16) char fsm[20736];
    int bid = blockIdx.x;
    int t = threadIdx.x;

    if (bid < 1664) {
        // ======== a0 / a0t: MFMA fp16, pipelined loads ========
        int xcd = bid & 7, s = bid >> 3;          // s in [0,208)
        int l = t & 63, w = t >> 6;
        int col = l & 15, q = l >> 4;

        int b, jh, pixg, estride;
        const float* srcb;
        float* dstb;
        if (s < 200) {                            // cand: 4 b x (2 jh x 25 pq)
            b = xcd * 4 + s / 50;
            int rest = s % 50;
            jh = rest / 25;
            int pq = rest % 25;
            pixg = pq * 16 + col;
            estride = 400;
            srcb = cand + (size_t)(b * 256 + q * 8) * 400 + pixg;
            dstb = A0f + ((size_t)(b * 400) + pixg) * 512 + jh * 256 + w * 64 + q * 4;
        } else {                                   // template: 4 b x 2 jh
            int s2 = s - 200;
            b = xcd * 4 + (s2 >> 1);
            jh = s2 & 1;
            pixg = col;
            estride = 16;
            srcb = tf + (size_t)(b * 256 + q * 8) * 16 + pixg;
            dstb = A0t + ((size_t)(b * 16) + pixg) * 512 + jh * 256 + w * 64 + q * 4;
        }

        const half8v* Ah = (const half8v*)g_wa0;
        f32x4 acc[4];
#pragma unroll
        for (int mt = 0; mt < 4; ++mt) acc[mt] = (f32x4){0.f, 0.f, 0.f, 0.f};

        float cur[8];
#pragma unroll
        for (int e = 0; e < 8; ++e) cur[e] = srcb[(size_t)e * estride];

#pragma unroll
        for (int k0 = 0; k0 < 8; ++k0) {
            float nxt[8];
            if (k0 < 7) {                          // T14: next iteration's loads first
                const float* cpn = srcb + (size_t)(k0 + 1) * 32 * estride;
#pragma unroll
                for (int e = 0; e < 8; ++e) nxt[e] = cpn[(size_t)e * estride];
            }
            half8v bv;
#pragma unroll
            for (int e = 0; e < 8; ++e) bv[e] = (_Float16)cur[e];
#pragma unroll
            for (int mt = 0; mt < 4; ++mt) {
                int jt = jh * 16 + w * 4 + mt;
                half8v ah = Ah[(jt * 8 + k0) * 64 + l];
                acc[mt] = __builtin_amdgcn_mfma_f32_16x16x32_f16(ah, bv, acc[mt], 0, 0, 0);
            }
            if (k0 < 7) {
#pragma unroll
                for (int e = 0; e < 8; ++e) cur[e] = nxt[e];
            }
        }
#pragma unroll
        for (int mt = 0; mt < 4; ++mt) {
            float4 st = { acc[mt][0], acc[mt][1], acc[mt][2], acc[mt][3] };
            *(float4*)(dstb + mt * 16) = st;
        }
    } else {
        // ======== transpose: candT[b][pix][ch] ========
        if (mode == 0) return;
        float (*tile)[81] = (float(*)[81])fsm;
        int blk = bid - 1664;
        int b = blk / 20, rest = blk % 20;
        int cg = rest / 5, pg = rest % 5;
        const float* src = cand + ((size_t)(b * 256 + cg * 64)) * 400 + pg * 80;
#pragma unroll
        for (int k = 0; k < 20; ++k) {
            int idx = k * 256 + t;
            int c = idx / 80, pix = idx % 80;
            tile[c][pix] = src[(size_t)c * 400 + pix];
        }
        __syncthreads();
#pragma unroll
        for (int k = 0; k < 20; ++k) {
            int idx = k * 256 + t;
            int pix = idx >> 6, c = idx & 63;
            float v = tile[c][pix];
            size_t off = ((size_t)(b * 400 + pg * 80 + pix)) * 256 + cg * 64 + c;
            if (mode == 2) ctF[off] = v;
            else           ctH[off] = f2us(v);
        }
    }
}

// ---------- m0_kernel: M0[b][r][j] = (1/16) sum_p A0f_mean[b][pix(r,p)][j] (separable, cand only) ----------
__global__ __launch_bounds__(256) void m0_kernel(
    const float* __restrict__ A0f, float* __restrict__ M0)
{
    int bid = blockIdx.x;               // 544 = 32 b x 17 y
    int b = bid / 17, y = bid % 17;
    int t = threadIdx.x;                // j in [0,256)
    const float* base = A0f + (size_t)b * 400 * 512;
    float cs[20];
#pragma unroll
    for (int xx = 0; xx < 20; ++xx) {
        float s = 0.f;
#pragma unroll
        for (int dy = 0; dy < 4; ++dy)
            s += base[(size_t)((y + dy) * 20 + xx) * 512 + t];
        cs[xx] = s;
    }
#pragma unroll
    for (int x = 0; x < 17; ++x) {
        float v = (cs[x] + cs[x + 1] + cs[x + 2] + cs[x + 3]) * 0.0625f;
        M0[((size_t)(b * 289 + y * 17 + x)) * 256 + t] = v;
    }
}

// ---------- persist_kernel: 256 blocks x 8 waves (512 thr); weights in LDS ----------
// LDS 118784 B (1 block/CU -> 2 waves/SIMD); VGPR free up to 256 (LDS-capped residency).
// CROSS-PATCH PIPELINE: pxl (64 loads) + m0q of the NEXT patch are issued right after L1
// (pxl's last consumer), overlapping the current patch's L2/L3/L4/softmax/pooling.
// Config ladder (measured): 512thr best; any thread/launch_bounds increase -> spill.
__global__ __launch_bounds__(512) void persist_kernel(
    const float* __restrict__ cand, const float* __restrict__ tf,
    const float* __restrict__ w4,
    const float* __restrict__ A0, const float* __restrict__ A0t,
    float* __restrict__ out,
    const float* __restrict__ ctF, const unsigned short* __restrict__ ctH, int mode,
    const float* __restrict__ M0, int use_m0k)
{
    __shared__ __align__(16) char smem[118784];
    const int WA1 = 0, WA2 = 65536, WA3 = 81920, STG = 86016;
    int t = threadIdx.x, l = t & 63, w = t >> 6;   // w in [0,8)

    {   // cooperative weight load (once per block)
        uint4* d1 = (uint4*)(smem + WA1); const uint4* s1 = (const uint4*)g_wp1;
        for (int i = t; i < 4096; i += 512) d1[i] = s1[i];
        uint4* d2 = (uint4*)(smem + WA2); const uint4* s2 = (const uint4*)g_wp2;
        for (int i = t; i < 1024; i += 512) d2[i] = s2[i];
        uint4* d3 = (uint4*)(smem + WA3); const uint4* s3 = (const uint4*)g_wp3;
        for (int i = t; i < 256; i += 512) d3[i] = s3[i];
    }
    __syncthreads();

    char* bufA = smem + STG + w * 4096;
    char* bufB = bufA + 2048;
    const half8v* A1 = (const half8v*)(smem + WA1);
    const half8v* A2 = (const half8v*)(smem + WA2);
    const half8v* A3 = (const half8v*)(smem + WA3);

    int bid = blockIdx.x;
    int xcd = bid & 7, slot = bid >> 3;            // 256 = 8 xcd * 32 slots
    int p_ = l & 15, q = l >> 4;

    // ---- current patch state + prologue prefetch ----
    bool is_t; int b, r; const float* afb; int pixo[16];
    float pxl[4][16]; float m0q[4]; bool m0_ok;
    {
        int j = slot * 8 + w;                      // always < 1160
        is_t = (j >= 1156);
        if (!is_t) {
            int idx = xcd * 1156 + j;
            b = idx / 289; r = idx % 289;
            int y = r / 17, x = r % 17;
            afb = A0 + (size_t)b * 400 * 512;
#pragma unroll
            for (int p = 0; p < 16; ++p) pixo[p] = (y + (p >> 2)) * 20 + x + (p & 3);
        } else {
            b = xcd * 4 + (j - 1156); r = 0;
            afb = A0t + (size_t)b * 16 * 512;
#pragma unroll
            for (int p = 0; p < 16; ++p) pixo[p] = p;
        }
#pragma unroll
        for (int qt = 0; qt < 4; ++qt)
#pragma unroll
            for (int p = 0; p < 16; ++p)
                pxl[qt][p] = afb[(size_t)pixo[p] * 512 + 256 + qt * 64 + l];
        m0_ok = (!is_t && use_m0k);
        if (m0_ok) {
            const float* mp = M0 + (size_t)(b * 289 + r) * 256 + l;
#pragma unroll
            for (int qt = 0; qt < 4; ++qt) m0q[qt] = mp[qt * 64];
        }
    }

    for (int j = slot * 8 + w; j < 1160; j += 256) {
        // ---- m0 fallback (template or no-m0k): via bufB, same as anchor ----
        if (!m0_ok) {
            float4 ms = {0.f, 0.f, 0.f, 0.f};
#pragma unroll
            for (int p = 0; p < 16; ++p) {
                float4 v = *(const float4*)(afb + (size_t)pixo[p] * 512 + 4 * l);
                ms.x += v.x; ms.y += v.y; ms.z += v.z; ms.w += v.w;
            }
            ms.x *= 0.0625f; ms.y *= 0.0625f; ms.z *= 0.0625f; ms.w *= 0.0625f;
            *(float4*)(bufB + l * 16) = ms;
        }

        // ---- layer 1: 4 quarters x 2 K-steps, M-tiles 0..7 (consumes pxl) ----
        f32x4 acc[8];
#pragma unroll
        for (int m = 0; m < 8; ++m) acc[m] = (f32x4){0.f, 0.f, 0.f, 0.f};

#pragma unroll
        for (int qt = 0; qt < 4; ++qt) {
            float m0c = m0_ok ? m0q[qt] : *(const float*)(bufB + (qt * 64 + l) * 4);
#pragma unroll
            for (int p = 0; p < 16; ++p) {
                float h = lrelu(m0c + pxl[qt][p]);
                int off = p * 128 + ((((l >> 3) ^ (p & 7))) << 4) + (l & 7) * 2;
                *(unsigned short*)(bufA + off) = f2hu(h);
            }
#pragma unroll
            for (int kk = 0; kk < 2; ++kk) {
                int off = p_ * 128 + ((((kk * 4 + q) ^ (p_ & 7))) << 4);
                half8v bq = *(const half8v*)(bufA + off);
                int k0g = qt * 2 + kk;
#pragma unroll
                for (int m = 0; m < 8; ++m) {
                    half8v ah = A1[(m * 8 + k0g) * 64 + l];
                    acc[m] = __builtin_amdgcn_mfma_f32_16x16x32_f16(ah, bq, acc[m], 0, 0, 0);
                }
            }
        }

        // ---- PREFETCH next patch (pxl dead after L1): overlaps L2/L3/L4/pooling ----
        int jn = j + 256;
        bool hasn = (jn < 1160);
        bool is_tn = false; int bn = 0, rn = 0;
        const float* afbn = afb; int pixon[16];
        float pxln[4][16]; float m0qn[4]; bool m0_okn = false;
#pragma unroll
        for (int p = 0; p < 16; ++p) pixon[p] = 0;
#pragma unroll
        for (int qt = 0; qt < 4; ++qt) {
            m0qn[qt] = 0.f;
#pragma unroll
            for (int p = 0; p < 16; ++p) pxln[qt][p] = 0.f;
        }
        if (hasn) {
            is_tn = (jn >= 1156);
            if (!is_tn) {
                int idx = xcd * 1156 + jn;
                bn = idx / 289; rn = idx % 289;
                int y = rn / 17, x = rn % 17;
                afbn = A0 + (size_t)bn * 400 * 512;
#pragma unroll
                for (int p = 0; p < 16; ++p) pixon[p] = (y + (p >> 2)) * 20 + x + (p & 3);
            } else {
                bn = xcd * 4 + (jn - 1156); rn = 0;
                afbn = A0t + (size_t)bn * 16 * 512;
#pragma unroll
                for (int p = 0; p < 16; ++p) pixon[p] = p;
            }
#pragma unroll
            for (int qt = 0; qt < 4; ++qt)
#pragma unroll
                for (int p = 0; p < 16; ++p)
                    pxln[qt][p] = afbn[(size_t)pixon[p] * 512 + 256 + qt * 64 + l];
            m0_okn = (!is_tn && use_m0k);
            if (m0_okn) {
                const float* mp = M0 + (size_t)(bn * 289 + rn) * 256 + l;
#pragma unroll
                for (int qt = 0; qt < 4; ++qt) m0qn[qt] = mp[qt * 64];
            }
        }

        // ---- layer 2: h1 staged in two halves through bufB ----
        f32x4 acc2[4];
#pragma unroll
        for (int m2 = 0; m2 < 4; ++m2) acc2[m2] = (f32x4){0.f, 0.f, 0.f, 0.f};

#pragma unroll
        for (int half = 0; half < 2; ++half) {
#pragma unroll
            for (int mm = 0; mm < 4; ++mm) {
                uint2 ph = pack_h4(acc[half * 4 + mm]);
                int off = p_ * 128 + ((((mm * 2 + (q >> 1)) ^ (p_ & 7))) << 4) + (q & 1) * 8;
                *(uint2*)(bufB + off) = ph;
            }
#pragma unroll
            for (int kf = 0; kf < 2; ++kf) {
                int off = p_ * 128 + ((((kf * 4 + q) ^ (p_ & 7))) << 4);
                half8v bq = *(const half8v*)(bufB + off);
                int kfg = half * 2 + kf;
#pragma unroll
                for (int m2 = 0; m2 < 4; ++m2) {
                    half8v ah = A2[(m2 * 4 + kfg) * 64 + l];
                    acc2[m2] = __builtin_amdgcn_mfma_f32_16x16x32_f16(ah, bq, acc2[m2], 0, 0, 0);
                }
            }
        }

        // ---- layer 3: h2 -> bufA ----
#pragma unroll
        for (int m2 = 0; m2 < 4; ++m2) {
            uint2 ph = pack_h4(acc2[m2]);
            int off = p_ * 128 + ((((m2 * 2 + (q >> 1)) ^ (p_ & 7))) << 4) + (q & 1) * 8;
            *(uint2*)(bufA + off) = ph;
        }
        f32x4 acc3[2];
        acc3[0] = (f32x4){0.f, 0.f, 0.f, 0.f};
        acc3[1] = (f32x4){0.f, 0.f, 0.f, 0.f};
#pragma unroll
        for (int k0 = 0; k0 < 2; ++k0) {
            int off = p_ * 128 + ((((k0 * 4 + q) ^ (p_ & 7))) << 4);
            half8v bq = *(const half8v*)(bufA + off);
#pragma unroll
            for (int mt = 0; mt < 2; ++mt) {
                half8v ah = A3[(mt * 2 + k0) * 64 + l];
                acc3[mt] = __builtin_amdgcn_mfma_f32_16x16x32_f16(ah, bq, acc3[mt], 0, 0, 0);
            }
        }

        // ---- layer 4 + softmax fully in registers ----
        float s4 = 0.f;
#pragma unroll
        for (int mt = 0; mt < 2; ++mt)
#pragma unroll
            for (int rg = 0; rg < 4; ++rg)
                s4 += w4[mt * 16 + q * 4 + rg] * lrelu(acc3[mt][rg]);
        s4 += __shfl_xor(s4, 16); s4 += __shfl_xor(s4, 32);
        float mx = s4;
#pragma unroll
        for (int msk = 8; msk; msk >>= 1) mx = fmaxf(mx, __shfl_xor(mx, msk));
        float e = __expf(s4 - mx), sum = e;
#pragma unroll
        for (int msk = 8; msk; msk >>= 1) sum += __shfl_xor(sum, msk);
        float wnl = e / sum;
        if (l < 16) *(float*)(bufB + l * 4) = wnl;
        float wnv[16];
#pragma unroll
        for (int p = 0; p < 16; ++p) wnv[p] = *(const float*)(bufB + p * 4);

        // ---- weighted pooling (current patch: uses pixo/b/r/is_t) ----
        if (is_t) {
            if (l < 16) out[b * 272 + 256 + l] = wnl;
#pragma unroll
            for (int ii = 0; ii < 4; ++ii) {
                int ch = ii * 64 + l;
                const float* tp = tf + (size_t)(b * 256 + ch) * 16;
                float a = 0.f;
#pragma unroll
                for (int p = 0; p < 16; ++p) a += tp[p] * wnv[p];
                out[b * 272 + ch] = a;
            }
        } else if (mode == 2) {
            const float* ct = ctF + (size_t)b * 400 * 256;
#pragma unroll
            for (int ii = 0; ii < 4; ++ii) {
                float a = 0.f;
#pragma unroll
                for (int p = 0; p < 16; ++p)
                    a += ct[(size_t)pixo[p] * 256 + ii * 64 + l] * wnv[p];
                out[8704 + (size_t)(b * 256 + ii * 64 + l) * 289 + r] = a;
            }
        } else if (mode == 1) {
            const unsigned short* ct = ctH + (size_t)b * 400 * 256;
#pragma unroll
            for (int ii = 0; ii < 4; ++ii) {
                float a = 0.f;
#pragma unroll
                for (int p = 0; p < 16; ++p)
                    a += us2f(ct[(size_t)pixo[p] * 256 + ii * 64 + l]) * wnv[p];
                out[8704 + (size_t)(b * 256 + ii * 64 + l) * 289 + r] = a;
            }
        } else {
            const float* cb = cand + (size_t)b * 256 * 400;
#pragma unroll
            for (int ii = 0; ii < 4; ++ii) {
                int ch = ii * 64 + l;
                const float* cp = cb + (size_t)ch * 400;
                float a = 0.f;
#pragma unroll
                for (int p = 0; p < 16; ++p) a += cp[pixo[p]] * wnv[p];
                out[8704 + (size_t)(b * 256 + ch) * 289 + r] = a;
            }
        }

        // ---- rotate prefetched state into current ----
        if (hasn) {
            is_t = is_tn; b = bn; r = rn; afb = afbn;
#pragma unroll
            for (int p = 0; p < 16; ++p) pixo[p] = pixon[p];
#pragma unroll
            for (int qt = 0; qt < 4; ++qt)
#pragma unroll
                for (int p = 0; p < 16; ++p) pxl[qt][p] = pxln[qt][p];
            m0_ok = m0_okn;
#pragma unroll
            for (int qt = 0; qt < 4; ++qt) m0q[qt] = m0qn[qt];
        }
    }
}

// ---------- launch ----------
extern "C" void kernel_launch(void* const* d_in, const int* in_sizes, int n_in,
                              void* d_out, int out_size, void* d_ws, size_t ws_size,
                              hipStream_t stream)
{
    const float* tf = (const float*)d_in[0];
    const float* cf = (const float*)d_in[1];
    const float* w0 = (const float*)d_in[2];
    const float* w1 = (const float*)d_in[3];
    const float* w2 = (const float*)d_in[4];
    const float* w3 = (const float*)d_in[5];
    const float* w4 = (const float*)d_in[6];
    float* out = (float*)d_out;

    const size_t A0_BYTES  = (size_t)32 * 400 * 512 * 4;  // 26.2 MB
    const size_t A0T_BYTES = (size_t)32 * 16 * 512 * 4;   //  1.0 MB
    const size_t CT_F32    = (size_t)32 * 400 * 256 * 4;  // 13.1 MB
    const size_t CT_BF16   = (size_t)32 * 400 * 256 * 2;  //  6.6 MB
    const size_t M0_BYTES  = (size_t)32 * 289 * 256 * 4;  //  9.5 MB

    float* A0f = (float*)d_ws;
    float* A0t = (float*)((char*)d_ws + A0_BYTES);
    char*  ctb = (char*)d_ws + A0_BYTES + A0T_BYTES;

    int mode = 0, use_m0k = 0;
    if (ws_size >= A0_BYTES + A0T_BYTES + CT_F32)       mode = 2;
    else if (ws_size >= A0_BYTES + A0T_BYTES + CT_BF16) mode = 1;
    if (mode == 2 && ws_size >= A0_BYTES + A0T_BYTES + CT_F32 + M0_BYTES) use_m0k = 1;
    float*          ctF = (float*)ctb;
    unsigned short* ctH = (unsigned short*)ctb;
    float*          M0  = (float*)(ctb + CT_F32);

    prep_kernel<<<680, 256, 0, stream>>>(w0, w1, w2, w3);
    front_kernel<<<2304, 256, 0, stream>>>(cf, tf, A0f, A0t, ctF, ctH, mode);
    if (use_m0k) m0_kernel<<<544, 256, 0, stream>>>(A0f, M0);
    persist_kernel<<<256, 512, 0, stream>>>(cf, tf, w4, A0f, A0t, out, ctF, ctH, mode, M0, use_m0k);
}

// Round 26
// 91.706 us; speedup vs baseline: 1.4738x; 1.4738x over previous
//
#include <hip/hip_runtime.h>
#include <hip/hip_bf16.h>
#include <hip/hip_fp16.h>

typedef __attribute__((ext_vector_type(8))) _Float16 half8v;  // 8 fp16 = 4 VGPR
typedef __attribute__((ext_vector_type(4))) float f32x4;

// ---------- packed weights (written by prep_kernel every launch) ----------
__device__ __align__(16) float g_w0T[256 * 512];                  // fp32 [c][j] (fallback/debug)
__device__ __align__(16) unsigned short g_wa0[32 * 8 * 64 * 8];   // a0 A-frags fp16 [jt][k0][l][e]
__device__ __align__(16) unsigned short g_wp1[8 * 8 * 64 * 8];    // L1 A-frags fp16 (64KB)
__device__ __align__(16) unsigned short g_wp2[4 * 4 * 64 * 8];    // L2 (16KB)
__device__ __align__(16) unsigned short g_wp3[2 * 2 * 64 * 8];    // L3 (4KB)

// ---------- helpers ----------
__device__ __forceinline__ float lrelu(float x) { return x >= 0.f ? x : 0.01f * x; }
__device__ __forceinline__ unsigned short f2hu(float x) {
    _Float16 h = (_Float16)x; return *(unsigned short*)&h;
}
__device__ __forceinline__ unsigned short f2us(float x) {   // bf16 (mode-1 candT only)
    __hip_bfloat16 h = __float2bfloat16(x); return *(unsigned short*)&h;
}
__device__ __forceinline__ float us2f(unsigned short u) {
    union { unsigned i; float f; } c; c.i = ((unsigned)u) << 16; return c.f;
}
__device__ __forceinline__ uint2 pack_h4(const f32x4& a) {
    unsigned short h[4];
#pragma unroll
    for (int i = 0; i < 4; ++i) h[i] = f2hu(lrelu(a[i]));
    uint2 r;
    r.x = (unsigned)h[0] | ((unsigned)h[1] << 16);
    r.y = (unsigned)h[2] | ((unsigned)h[3] << 16);
    return r;
}

// ---------- prep: w0T fp32, a0/L1..L3 A-frags (fp16) ----------
__global__ __launch_bounds__(256) void prep_kernel(
    const float* __restrict__ w0, const float* __restrict__ w1,
    const float* __restrict__ w2, const float* __restrict__ w3)
{
    int id = blockIdx.x * 256 + threadIdx.x;
    int stride = gridDim.x * 256;
    for (int i = id; i < 256 * 512; i += stride) {        // w0T[c][j] fp32
        int c = i >> 9, j = i & 511;
        g_w0T[i] = (j < 256) ? w0[j * 512 + c] : w0[(j - 256) * 512 + 256 + c];
    }
    for (int i = id; i < 32 * 8 * 64 * 8; i += stride) {  // a0 A-frags
        int e = i & 7, l = (i >> 3) & 63, k0 = (i >> 9) & 7, jt = i >> 12;
        int c = k0 * 32 + ((l >> 4) * 8) + e;
        int j = jt * 16 + (l & 15);
        float v = (j < 256) ? w0[j * 512 + c] : w0[(j - 256) * 512 + 256 + c];
        g_wa0[i] = f2hu(v);
    }
    for (int i = id; i < 8 * 8 * 64 * 8; i += stride) {   // L1: 128x256
        int e = i & 7, l = (i >> 3) & 63, k0 = (i >> 9) & 7, m = i >> 12;
        int oc = m * 16 + (l & 15), c = k0 * 32 + ((l >> 4) * 8) + e;
        g_wp1[i] = f2hu(w1[oc * 256 + c]);
    }
    for (int i = id; i < 4 * 4 * 64 * 8; i += stride) {   // L2: 64x128
        int e = i & 7, l = (i >> 3) & 63, k0 = (i >> 9) & 3, m = i >> 11;
        int oc = m * 16 + (l & 15), c = k0 * 32 + ((l >> 4) * 8) + e;
        g_wp2[i] = f2hu(w2[oc * 128 + c]);
    }
    for (int i = id; i < 2 * 2 * 64 * 8; i += stride) {   // L3: 32x64
        int e = i & 7, l = (i >> 3) & 63, k0 = (i >> 9) & 1, m = i >> 10;
        int oc = m * 16 + (l & 15), c = k0 * 32 + ((l >> 4) * 8) + e;
        g_wp3[i] = f2hu(w3[oc * 64 + c]);
    }
}

// ---------- front_kernel: a0 (blocks 0..1663, incl. template A0t) | transpose (1664..2303) ----------
__global__ __launch_bounds__(256) void front_kernel(
    const float* __restrict__ cand, const float* __restrict__ tf,
    float* __restrict__ A0f, float* __restrict__ A0t,
    float* __restrict__ ctF, unsigned short* __restrict__ ctH, int mode)
{
    __shared__ __align__(16) char fsm[20736];
    int bid = blockIdx.x;
    int t = threadIdx.x;

    if (bid < 1664) {
        // ======== a0 / a0t: MFMA fp16, pipelined loads ========
        int xcd = bid & 7, s = bid >> 3;          // s in [0,208)
        int l = t & 63, w = t >> 6;
        int col = l & 15, q = l >> 4;

        int b, jh, pixg, estride;
        const float* srcb;
        float* dstb;
        if (s < 200) {                            // cand: 4 b x (2 jh x 25 pq)
            b = xcd * 4 + s / 50;
            int rest = s % 50;
            jh = rest / 25;
            int pq = rest % 25;
            pixg = pq * 16 + col;
            estride = 400;
            srcb = cand + (size_t)(b * 256 + q * 8) * 400 + pixg;
            dstb = A0f + ((size_t)(b * 400) + pixg) * 512 + jh * 256 + w * 64 + q * 4;
        } else {                                   // template: 4 b x 2 jh
            int s2 = s - 200;
            b = xcd * 4 + (s2 >> 1);
            jh = s2 & 1;
            pixg = col;
            estride = 16;
            srcb = tf + (size_t)(b * 256 + q * 8) * 16 + pixg;
            dstb = A0t + ((size_t)(b * 16) + pixg) * 512 + jh * 256 + w * 64 + q * 4;
        }

        const half8v* Ah = (const half8v*)g_wa0;
        f32x4 acc[4];
#pragma unroll
        for (int mt = 0; mt < 4; ++mt) acc[mt] = (f32x4){0.f, 0.f, 0.f, 0.f};

        float cur[8];
#pragma unroll
        for (int e = 0; e < 8; ++e) cur[e] = srcb[(size_t)e * estride];

#pragma unroll
        for (int k0 = 0; k0 < 8; ++k0) {
            float nxt[8];
            if (k0 < 7) {                          // T14: next iteration's loads first
                const float* cpn = srcb + (size_t)(k0 + 1) * 32 * estride;
#pragma unroll
                for (int e = 0; e < 8; ++e) nxt[e] = cpn[(size_t)e * estride];
            }
            half8v bv;
#pragma unroll
            for (int e = 0; e < 8; ++e) bv[e] = (_Float16)cur[e];
#pragma unroll
            for (int mt = 0; mt < 4; ++mt) {
                int jt = jh * 16 + w * 4 + mt;
                half8v ah = Ah[(jt * 8 + k0) * 64 + l];
                acc[mt] = __builtin_amdgcn_mfma_f32_16x16x32_f16(ah, bv, acc[mt], 0, 0, 0);
            }
            if (k0 < 7) {
#pragma unroll
                for (int e = 0; e < 8; ++e) cur[e] = nxt[e];
            }
        }
#pragma unroll
        for (int mt = 0; mt < 4; ++mt) {
            float4 st = { acc[mt][0], acc[mt][1], acc[mt][2], acc[mt][3] };
            *(float4*)(dstb + mt * 16) = st;
        }
    } else {
        // ======== transpose: candT[b][pix][ch] ========
        if (mode == 0) return;
        float (*tile)[81] = (float(*)[81])fsm;
        int blk = bid - 1664;
        int b = blk / 20, rest = blk % 20;
        int cg = rest / 5, pg = rest % 5;
        const float* src = cand + ((size_t)(b * 256 + cg * 64)) * 400 + pg * 80;
#pragma unroll
        for (int k = 0; k < 20; ++k) {
            int idx = k * 256 + t;
            int c = idx / 80, pix = idx % 80;
            tile[c][pix] = src[(size_t)c * 400 + pix];
        }
        __syncthreads();
#pragma unroll
        for (int k = 0; k < 20; ++k) {
            int idx = k * 256 + t;
            int pix = idx >> 6, c = idx & 63;
            float v = tile[c][pix];
            size_t off = ((size_t)(b * 400 + pg * 80 + pix)) * 256 + cg * 64 + c;
            if (mode == 2) ctF[off] = v;
            else           ctH[off] = f2us(v);
        }
    }
}

// ---------- m0_kernel: M0[b][r][j] = (1/16) sum_p A0f_mean[b][pix(r,p)][j] (separable, cand only) ----------
__global__ __launch_bounds__(256) void m0_kernel(
    const float* __restrict__ A0f, float* __restrict__ M0)
{
    int bid = blockIdx.x;               // 544 = 32 b x 17 y
    int b = bid / 17, y = bid % 17;
    int t = threadIdx.x;                // j in [0,256)
    const float* base = A0f + (size_t)b * 400 * 512;
    float cs[20];
#pragma unroll
    for (int xx = 0; xx < 20; ++xx) {
        float s = 0.f;
#pragma unroll
        for (int dy = 0; dy < 4; ++dy)
            s += base[(size_t)((y + dy) * 20 + xx) * 512 + t];
        cs[xx] = s;
    }
#pragma unroll
    for (int x = 0; x < 17; ++x) {
        float v = (cs[x] + cs[x + 1] + cs[x + 2] + cs[x + 3]) * 0.0625f;
        M0[((size_t)(b * 289 + y * 17 + x)) * 256 + t] = v;
    }
}

// ---------- persist_kernel: 256 blocks x 8 waves (512 thr); weights in LDS ----------
// LDS 118784 B (1 block/CU -> 2 waves/SIMD); 112 VGPR, no spill. SESSION-BEST CONFIG (91.7us):
// pxl[4][16] hoist (all 64 pixel-half loads up-front, single latency exposure).
// Closed levers (measured): 768/1024thr & launch_bounds hints -> spill; 80KB LDS no co-schedule;
// cross-patch prefetch -> 128-VGPR wall, rematerialization, 2x slower.
__global__ __launch_bounds__(512) void persist_kernel(
    const float* __restrict__ cand, const float* __restrict__ tf,
    const float* __restrict__ w4,
    const float* __restrict__ A0, const float* __restrict__ A0t,
    float* __restrict__ out,
    const float* __restrict__ ctF, const unsigned short* __restrict__ ctH, int mode,
    const float* __restrict__ M0, int use_m0k)
{
    __shared__ __align__(16) char smem[118784];
    const int WA1 = 0, WA2 = 65536, WA3 = 81920, STG = 86016;
    int t = threadIdx.x, l = t & 63, w = t >> 6;   // w in [0,8)

    {   // cooperative weight load (once per block)
        uint4* d1 = (uint4*)(smem + WA1); const uint4* s1 = (const uint4*)g_wp1;
        for (int i = t; i < 4096; i += 512) d1[i] = s1[i];
        uint4* d2 = (uint4*)(smem + WA2); const uint4* s2 = (const uint4*)g_wp2;
        for (int i = t; i < 1024; i += 512) d2[i] = s2[i];
        uint4* d3 = (uint4*)(smem + WA3); const uint4* s3 = (const uint4*)g_wp3;
        for (int i = t; i < 256; i += 512) d3[i] = s3[i];
    }
    __syncthreads();

    char* bufA = smem + STG + w * 4096;
    char* bufB = bufA + 2048;
    const half8v* A1 = (const half8v*)(smem + WA1);
    const half8v* A2 = (const half8v*)(smem + WA2);
    const half8v* A3 = (const half8v*)(smem + WA3);

    int bid = blockIdx.x;
    int xcd = bid & 7, slot = bid >> 3;            // 256 = 8 xcd * 32 slots
    int p_ = l & 15, q = l >> 4;

    // per-xcd work: 1156 cand patches + 4 template patches (j = 1156..1159)
    for (int j = slot * 8 + w; j < 1160; j += 256) {
        bool is_t = (j >= 1156);
        int b, r = 0;
        const float* afb;
        int pixo[16];
        if (!is_t) {
            int idx = xcd * 1156 + j;
            b = idx / 289; r = idx % 289;
            int y = r / 17, x = r % 17;
            afb = A0 + (size_t)b * 400 * 512;
#pragma unroll
            for (int p = 0; p < 16; ++p) pixo[p] = (y + (p >> 2)) * 20 + x + (p & 3);
        } else {
            b = xcd * 4 + (j - 1156);
            afb = A0t + (size_t)b * 16 * 512;
#pragma unroll
            for (int p = 0; p < 16; ++p) pixo[p] = p;
        }

        // ---- hoist ALL pixel-half loads (64) up-front: single latency exposure ----
        float pxl[4][16];
#pragma unroll
        for (int qt = 0; qt < 4; ++qt)
#pragma unroll
            for (int p = 0; p < 16; ++p)
                pxl[qt][p] = afb[(size_t)pixo[p] * 512 + 256 + qt * 64 + l];

        float m0q[4];
        bool m0_reg = (!is_t && use_m0k);
        if (m0_reg) {
            const float* mp = M0 + (size_t)(b * 289 + r) * 256 + l;
#pragma unroll
            for (int qt = 0; qt < 4; ++qt) m0q[qt] = mp[qt * 64];
        } else {
            float4 ms = {0.f, 0.f, 0.f, 0.f};
#pragma unroll
            for (int p = 0; p < 16; ++p) {
                float4 v = *(const float4*)(afb + (size_t)pixo[p] * 512 + 4 * l);
                ms.x += v.x; ms.y += v.y; ms.z += v.z; ms.w += v.w;
            }
            ms.x *= 0.0625f; ms.y *= 0.0625f; ms.z *= 0.0625f; ms.w *= 0.0625f;
            *(float4*)(bufB + l * 16) = ms;
        }

        // ---- layer 1: 4 quarters x 2 K-steps, M-tiles 0..7 ----
        f32x4 acc[8];
#pragma unroll
        for (int m = 0; m < 8; ++m) acc[m] = (f32x4){0.f, 0.f, 0.f, 0.f};

#pragma unroll
        for (int qt = 0; qt < 4; ++qt) {
            float m0c = m0_reg ? m0q[qt] : *(const float*)(bufB + (qt * 64 + l) * 4);
#pragma unroll
            for (int p = 0; p < 16; ++p) {
                float h = lrelu(m0c + pxl[qt][p]);
                int off = p * 128 + ((((l >> 3) ^ (p & 7))) << 4) + (l & 7) * 2;
                *(unsigned short*)(bufA + off) = f2hu(h);
            }
#pragma unroll
            for (int kk = 0; kk < 2; ++kk) {
                int off = p_ * 128 + ((((kk * 4 + q) ^ (p_ & 7))) << 4);
                half8v bq = *(const half8v*)(bufA + off);
                int k0g = qt * 2 + kk;
#pragma unroll
                for (int m = 0; m < 8; ++m) {
                    half8v ah = A1[(m * 8 + k0g) * 64 + l];
                    acc[m] = __builtin_amdgcn_mfma_f32_16x16x32_f16(ah, bq, acc[m], 0, 0, 0);
                }
            }
        }

        // ---- layer 2: h1 staged in two halves through bufB ----
        f32x4 acc2[4];
#pragma unroll
        for (int m2 = 0; m2 < 4; ++m2) acc2[m2] = (f32x4){0.f, 0.f, 0.f, 0.f};

#pragma unroll
        for (int half = 0; half < 2; ++half) {
#pragma unroll
            for (int mm = 0; mm < 4; ++mm) {
                uint2 ph = pack_h4(acc[half * 4 + mm]);
                int off = p_ * 128 + ((((mm * 2 + (q >> 1)) ^ (p_ & 7))) << 4) + (q & 1) * 8;
                *(uint2*)(bufB + off) = ph;
            }
#pragma unroll
            for (int kf = 0; kf < 2; ++kf) {
                int off = p_ * 128 + ((((kf * 4 + q) ^ (p_ & 7))) << 4);
                half8v bq = *(const half8v*)(bufB + off);
                int kfg = half * 2 + kf;
#pragma unroll
                for (int m2 = 0; m2 < 4; ++m2) {
                    half8v ah = A2[(m2 * 4 + kfg) * 64 + l];
                    acc2[m2] = __builtin_amdgcn_mfma_f32_16x16x32_f16(ah, bq, acc2[m2], 0, 0, 0);
                }
            }
        }

        // ---- layer 3: h2 -> bufA ----
#pragma unroll
        for (int m2 = 0; m2 < 4; ++m2) {
            uint2 ph = pack_h4(acc2[m2]);
            int off = p_ * 128 + ((((m2 * 2 + (q >> 1)) ^ (p_ & 7))) << 4) + (q & 1) * 8;
            *(uint2*)(bufA + off) = ph;
        }
        f32x4 acc3[2];
        acc3[0] = (f32x4){0.f, 0.f, 0.f, 0.f};
        acc3[1] = (f32x4){0.f, 0.f, 0.f, 0.f};
#pragma unroll
        for (int k0 = 0; k0 < 2; ++k0) {
            int off = p_ * 128 + ((((k0 * 4 + q) ^ (p_ & 7))) << 4);
            half8v bq = *(const half8v*)(bufA + off);
#pragma unroll
            for (int mt = 0; mt < 2; ++mt) {
                half8v ah = A3[(mt * 2 + k0) * 64 + l];
                acc3[mt] = __builtin_amdgcn_mfma_f32_16x16x32_f16(ah, bq, acc3[mt], 0, 0, 0);
            }
        }

        // ---- layer 4 + softmax fully in registers ----
        float s4 = 0.f;
#pragma unroll
        for (int mt = 0; mt < 2; ++mt)
#pragma unroll
            for (int rg = 0; rg < 4; ++rg)
                s4 += w4[mt * 16 + q * 4 + rg] * lrelu(acc3[mt][rg]);
        s4 += __shfl_xor(s4, 16); s4 += __shfl_xor(s4, 32);
        float mx = s4;
#pragma unroll
        for (int msk = 8; msk; msk >>= 1) mx = fmaxf(mx, __shfl_xor(mx, msk));
        float e = __expf(s4 - mx), sum = e;
#pragma unroll
        for (int msk = 8; msk; msk >>= 1) sum += __shfl_xor(sum, msk);
        float wnl = e / sum;
        if (l < 16) *(float*)(bufB + l * 4) = wnl;
        float wnv[16];
#pragma unroll
        for (int p = 0; p < 16; ++p) wnv[p] = *(const float*)(bufB + p * 4);

        // ---- weighted pooling ----
        if (is_t) {
            if (l < 16) out[b * 272 + 256 + l] = wnl;
#pragma unroll
            for (int ii = 0; ii < 4; ++ii) {
                int ch = ii * 64 + l;
                const float* tp = tf + (size_t)(b * 256 + ch) * 16;
                float a = 0.f;
#pragma unroll
                for (int p = 0; p < 16; ++p) a += tp[p] * wnv[p];
                out[b * 272 + ch] = a;
            }
        } else if (mode == 2) {
            const float* ct = ctF + (size_t)b * 400 * 256;
#pragma unroll
            for (int ii = 0; ii < 4; ++ii) {
                float a = 0.f;
#pragma unroll
                for (int p = 0; p < 16; ++p)
                    a += ct[(size_t)pixo[p] * 256 + ii * 64 + l] * wnv[p];
                out[8704 + (size_t)(b * 256 + ii * 64 + l) * 289 + r] = a;
            }
        } else if (mode == 1) {
            const unsigned short* ct = ctH + (size_t)b * 400 * 256;
#pragma unroll
            for (int ii = 0; ii < 4; ++ii) {
                float a = 0.f;
#pragma unroll
                for (int p = 0; p < 16; ++p)
                    a += us2f(ct[(size_t)pixo[p] * 256 + ii * 64 + l]) * wnv[p];
                out[8704 + (size_t)(b * 256 + ii * 64 + l) * 289 + r] = a;
            }
        } else {
            const float* cb = cand + (size_t)b * 256 * 400;
#pragma unroll
            for (int ii = 0; ii < 4; ++ii) {
                int ch = ii * 64 + l;
                const float* cp = cb + (size_t)ch * 400;
                float a = 0.f;
#pragma unroll
                for (int p = 0; p < 16; ++p) a += cp[pixo[p]] * wnv[p];
                out[8704 + (size_t)(b * 256 + ch) * 289 + r] = a;
            }
        }
    }
}

// ---------- launch ----------
extern "C" void kernel_launch(void* const* d_in, const int* in_sizes, int n_in,
                              void* d_out, int out_size, void* d_ws, size_t ws_size,
                              hipStream_t stream)
{
    const float* tf = (const float*)d_in[0];
    const float* cf = (const float*)d_in[1];
    const float* w0 = (const float*)d_in[2];
    const float* w1 = (const float*)d_in[3];
    const float* w2 = (const float*)d_in[4];
    const float* w3 = (const float*)d_in[5];
    const float* w4 = (const float*)d_in[6];
    float* out = (float*)d_out;

    const size_t A0_BYTES  = (size_t)32 * 400 * 512 * 4;  // 26.2 MB
    const size_t A0T_BYTES = (size_t)32 * 16 * 512 * 4;   //  1.0 MB
    const size_t CT_F32    = (size_t)32 * 400 * 256 * 4;  // 13.1 MB
    const size_t CT_BF16   = (size_t)32 * 400 * 256 * 2;  //  6.6 MB
    const size_t M0_BYTES  = (size_t)32 * 289 * 256 * 4;  //  9.5 MB

    float* A0f = (float*)d_ws;
    float* A0t = (float*)((char*)d_ws + A0_BYTES);
    char*  ctb = (char*)d_ws + A0_BYTES + A0T_BYTES;

    int mode = 0, use_m0k = 0;
    if (ws_size >= A0_BYTES + A0T_BYTES + CT_F32)       mode = 2;
    else if (ws_size >= A0_BYTES + A0T_BYTES + CT_BF16) mode = 1;
    if (mode == 2 && ws_size >= A0_BYTES + A0T_BYTES + CT_F32 + M0_BYTES) use_m0k = 1;
    float*          ctF = (float*)ctb;
    unsigned short* ctH = (unsigned short*)ctb;
    float*          M0  = (float*)(ctb + CT_F32);

    prep_kernel<<<680, 256, 0, stream>>>(w0, w1, w2, w3);
    front_kernel<<<2304, 256, 0, stream>>>(cf, tf, A0f, A0t, ctF, ctH, mode);
    if (use_m0k) m0_kernel<<<544, 256, 0, stream>>>(A0f, M0);
    persist_kernel<<<256, 512, 0, stream>>>(cf, tf, w4, A0f, A0t, out, ctF, ctH, mode, M0, use_m0k);
}